// Round 12
// baseline (527.588 us; speedup 1.0000x reference)
//
#include <hip/hip_runtime.h>
#include <hip/hip_bf16.h>
#include <math.h>

#define NU   8000
#define NI   16000
#define NN   24000
#define DD   64
#define NL   2
#define NNZS 768000
#define KD   192        // 3 * 64 concat width
#define NCH  25         // column chunks
#define ACHUNK 640      // 16000 / NCH
#define CTILES 5        // ACHUNK / 128
#define RBLK4 32        // ceil(8000/256) row blocks (M=256 per block)
#define CBLK 125        // 16000/128 col blocks
#define SCH  24         // scan blocks

typedef __attribute__((ext_vector_type(8))) short  short8;
typedef __attribute__((ext_vector_type(4))) float  f32x4;

__device__ __forceinline__ unsigned short f2bf(float x) {
    union { float f; unsigned int u; } v; v.f = x;
    unsigned int r = v.u + 0x7fff + ((v.u >> 16) & 1);   // round-nearest-even
    return (unsigned short)(r >> 16);
}
__device__ __forceinline__ float bf2f(unsigned short u) {
    union { unsigned int u; float f; } v; v.u = ((unsigned int)u) << 16;
    return v.f;
}

// B-tile LDS layout: slot for (nf,kt,g,r16) = ((kt*8+nf)*4+g)*16+r16, XOR (g+4kt)&7
__device__ __forceinline__ int bslot(int nf, int kt, int g, int r16) {
    return ((((kt * 8 + nf) * 4 + g) * 16) + r16) ^ ((g + 4 * kt) & 7);
}

// ---------------- concat -> all_emb[:,0:64] bf16; zero hist; W -> bf16
__global__ void k_concat(const int* __restrict__ uidx, const int* __restrict__ iidx,
                         const float* __restrict__ ue, const float* __restrict__ ie,
                         const float* __restrict__ gcW, const float* __restrict__ biW,
                         unsigned short* __restrict__ allemb,
                         unsigned short* __restrict__ wbf, int* __restrict__ cnt) {
    int t = blockIdx.x * blockDim.x + threadIdx.x;
    if (t < NN) cnt[t] = 0;
    if (t < NL * DD * DD) {
        wbf[t] = f2bf(gcW[t]);
        wbf[NL * DD * DD + t] = f2bf(biW[t]);
    }
    if (t >= NN * DD) return;
    int n = t >> 6, d = t & 63;
    float v = (n < NU) ? ue[uidx[n] * DD + d] : ie[iidx[n - NU] * DD + d];
    allemb[(size_t)n * KD + d] = f2bf(v);
}

// ---------------- CSR build: histogram -> parallel 3-phase scan -> scatter
__global__ void k_hist(const int* __restrict__ rows, int* __restrict__ cnt) {
    int e = blockIdx.x * blockDim.x + threadIdx.x;
    if (e < NNZS) atomicAdd(&cnt[rows[e]], 1);
}

__global__ __launch_bounds__(1024) void k_scan1(const int* __restrict__ cnt,
                                                int* __restrict__ rp, int* __restrict__ btot) {
    __shared__ int wsum[16];
    int tid = threadIdx.x, lane = tid & 63, wid = tid >> 6;
    int i = blockIdx.x * 1024 + tid;
    int v = (i < NN) ? cnt[i] : 0;
    int x = v;
#pragma unroll
    for (int off = 1; off < 64; off <<= 1) {
        int t = __shfl_up(x, off, 64);
        if (lane >= off) x += t;
    }
    if (lane == 63) wsum[wid] = x;
    __syncthreads();
    if (tid < 16) {
        int y = wsum[tid];
#pragma unroll
        for (int off = 1; off < 16; off <<= 1) {
            int t = __shfl_up(y, off, 64);
            if (tid >= off) y += t;
        }
        wsum[tid] = y;
    }
    __syncthreads();
    int incl = x + (wid ? wsum[wid - 1] : 0);
    if (i < NN) rp[i + 1] = incl;
    if (tid == 0) btot[blockIdx.x] = wsum[15];
}

__global__ void k_scan2(const int* __restrict__ btot, int* __restrict__ boff) {
    int tid = threadIdx.x;   // 64 threads
    int v = (tid < SCH) ? btot[tid] : 0;
    int x = v;
#pragma unroll
    for (int off = 1; off < 32; off <<= 1) {
        int t = __shfl_up(x, off, 64);
        if (tid >= off) x += t;
    }
    if (tid < SCH) boff[tid] = x - v;
}

__global__ __launch_bounds__(1024) void k_scan3(const int* __restrict__ cnt,
                                                const int* __restrict__ boff,
                                                int* __restrict__ rp, int* __restrict__ wp) {
    int i = blockIdx.x * 1024 + threadIdx.x;
    if (i == 0) rp[0] = 0;
    if (i >= NN) return;
    int g = rp[i + 1] + boff[blockIdx.x];
    rp[i + 1] = g;
    wp[i] = g - cnt[i];
}

__global__ void k_scatter(const int* __restrict__ rows, const int* __restrict__ cols,
                          const float* __restrict__ vals, int* __restrict__ wp,
                          int2* __restrict__ edat) {
    int e = blockIdx.x * blockDim.x + threadIdx.x;
    if (e >= NNZS) return;
    int r = rows[e];
    int pos = atomicAdd(&wp[r], 1);
    edat[pos] = make_int2(cols[e], __float_as_int(vals[e]));
}

// ---------------- side[r] = sum_e val_e * feat[col_e]: bf16 gather, one wave/row, full TLP
__global__ void k_spmm_csr(const int* __restrict__ rp, const int2* __restrict__ edat,
                           const unsigned short* __restrict__ feat, float* __restrict__ side) {
    int lane = threadIdx.x & 63;
    int wave = (blockIdx.x * blockDim.x + threadIdx.x) >> 6;
    int nw   = (gridDim.x * blockDim.x) >> 6;
    for (int r = wave; r < NN; r += nw) {
        int e0 = rp[r], e1 = rp[r + 1];
        float acc = 0.f;
        int e = e0;
        for (; e + 8 <= e1; e += 8) {
            int2 d[8];
#pragma unroll
            for (int j = 0; j < 8; ++j) d[j] = edat[e + j];
#pragma unroll
            for (int j = 0; j < 8; ++j)
                acc = fmaf(__int_as_float(d[j].y), bf2f(feat[(size_t)d[j].x * KD + lane]), acc);
        }
        for (; e < e1; ++e) {
            int2 d = edat[e];
            acc = fmaf(__int_as_float(d.y), bf2f(feat[(size_t)d.x * KD + lane]), acc);
        }
        side[(size_t)r * DD + lane] = acc;
    }
}

// ---------------- dense layer via MFMA
__global__ __launch_bounds__(256) void k_dense(const float* __restrict__ side,
                        unsigned short* __restrict__ allemb, int l,
                        const unsigned short* __restrict__ wg_bf,
                        const unsigned short* __restrict__ wb_bf,
                        const float* __restrict__ gcb, const float* __restrict__ bib) {
    int lane = threadIdx.x & 63;
    int wave = threadIdx.x >> 6;
    int n0 = (blockIdx.x * 4 + wave) * 16;
    int nrow = lane & 15;
    int kofs = (lane >> 4) * 8;
    const unsigned short* feat = allemb + l * DD;

    short8 bg[4][2], bb[4][2];
#pragma unroll
    for (int nf = 0; nf < 4; ++nf)
#pragma unroll
        for (int kt = 0; kt < 2; ++kt) {
            bg[nf][kt] = *(const short8*)(wg_bf + (nf * 16 + nrow) * DD + kt * 32 + kofs);
            bb[nf][kt] = *(const short8*)(wb_bf + (nf * 16 + nrow) * DD + kt * 32 + kofs);
        }

    short8 a1[2], a2[2];
    const float* sp = side + (size_t)(n0 + nrow) * DD;
    const unsigned short* ep = feat + (size_t)(n0 + nrow) * KD;
#pragma unroll
    for (int kt = 0; kt < 2; ++kt) {
        int o = kt * 32 + kofs;
#pragma unroll
        for (int j = 0; j < 8; ++j) {
            float s = sp[o + j];
            float e = bf2f(ep[o + j]);
            a1[kt][j] = (short)f2bf(s);
            a2[kt][j] = (short)f2bf(e * s);
        }
    }

    f32x4 acc1[4], acc2[4];
#pragma unroll
    for (int nf = 0; nf < 4; ++nf) { acc1[nf] = (f32x4){0,0,0,0}; acc2[nf] = (f32x4){0,0,0,0}; }
#pragma unroll
    for (int nf = 0; nf < 4; ++nf)
#pragma unroll
        for (int kt = 0; kt < 2; ++kt) {
            acc1[nf] = __builtin_amdgcn_mfma_f32_16x16x32_bf16(a1[kt], bg[nf][kt], acc1[nf], 0, 0, 0);
            acc2[nf] = __builtin_amdgcn_mfma_f32_16x16x32_bf16(a2[kt], bb[nf][kt], acc2[nf], 0, 0, 0);
        }

    int g = lane >> 4;
#pragma unroll
    for (int nf = 0; nf < 4; ++nf) {
        int o = nf * 16 + nrow;
        float b1 = gcb[o], b2 = bib[o];
#pragma unroll
        for (int r = 0; r < 4; ++r) {
            int node = n0 + g * 4 + r;
            float v1 = acc1[nf][r] + b1;
            float v2 = acc2[nf][r] + b2;
            v1 = v1 > 0.f ? v1 : 0.01f * v1;
            v2 = v2 > 0.f ? v2 : 0.01f * v2;
            allemb[(size_t)node * KD + (l + 1) * DD + o] = f2bf(v1 + v2);
        }
    }
}

// ---------------- kernel A: online (m, sum-exp) partials, M=256/block (64 rows/wave, mi=4)
// grid RBLK4*NCH rowblk-fast; B reg-staged into permuted LDS (round-10 mechanism)
__global__ __launch_bounds__(256) void k_lse_part(const unsigned short* __restrict__ allemb,
                                                  float* __restrict__ pm, float* __restrict__ ps) {
    __shared__ short8 Bs[3072];   // 49152 B
    int id = blockIdx.x;
    int rowblk = id % RBLK4;
    int chunk  = id / RBLK4;
    int tid = threadIdx.x;
    int lane = tid & 63;
    int wave = tid >> 6;
    int r0 = rowblk * 256 + wave * 64;
    int c0 = chunk * ACHUNK;
    const unsigned short* A = allemb;
    const unsigned short* B = allemb + (size_t)NU * KD;
    int kofs = (lane >> 4) * 8;
    int g = lane >> 4;

    short8 a[4][6];
#pragma unroll
    for (int mi = 0; mi < 4; ++mi) {
        int ar = r0 + mi * 16 + (lane & 15);
        if (ar >= NU) ar = NU - 1;    // ragged row guard
#pragma unroll
        for (int kt = 0; kt < 6; ++kt)
            a[mi][kt] = *(const short8*)(A + (size_t)ar * KD + kt * 32 + kofs);
    }

    float m[4][4], s[4][4];
#pragma unroll
    for (int mi = 0; mi < 4; ++mi)
#pragma unroll
        for (int r = 0; r < 4; ++r) { m[mi][r] = -INFINITY; s[mi][r] = 0.f; }

    for (int t = 0; t < CTILES; ++t) {
        const unsigned short* Bt = B + (size_t)(c0 + t * 128) * KD;
        __syncthreads();
#pragma unroll
        for (int i = 0; i < 12; ++i) {
            int mm = i * 256 + tid;
            int r = mm / 24, c = mm - r * 24;
            int kt = c >> 2, gg = c & 3;
            Bs[bslot(r >> 4, kt, gg, r & 15)] = *(const short8*)(Bt + (size_t)r * KD + c * 8);
        }
        __syncthreads();

        f32x4 acc[4][8];
#pragma unroll
        for (int mi = 0; mi < 4; ++mi)
#pragma unroll
            for (int nf = 0; nf < 8; ++nf) acc[mi][nf] = (f32x4){0.f, 0.f, 0.f, 0.f};
#pragma unroll
        for (int nf = 0; nf < 8; ++nf)
#pragma unroll
            for (int kt = 0; kt < 6; ++kt) {
                short8 b = Bs[bslot(nf, kt, g, lane & 15)];
#pragma unroll
                for (int mi = 0; mi < 4; ++mi)
                    acc[mi][nf] = __builtin_amdgcn_mfma_f32_16x16x32_bf16(a[mi][kt], b, acc[mi][nf], 0, 0, 0);
            }
#pragma unroll
        for (int mi = 0; mi < 4; ++mi)
#pragma unroll
            for (int r = 0; r < 4; ++r) {
                float lm = acc[mi][0][r];
#pragma unroll
                for (int nf = 1; nf < 8; ++nf) lm = fmaxf(lm, acc[mi][nf][r]);
                float nm = fmaxf(m[mi][r], lm);
                float p = 0.f;
#pragma unroll
                for (int nf = 0; nf < 8; ++nf) p += __expf(acc[mi][nf][r] - nm);
                s[mi][r] = s[mi][r] * __expf(m[mi][r] - nm) + p;
                m[mi][r] = nm;
            }
    }
#pragma unroll
    for (int mi = 0; mi < 4; ++mi)
#pragma unroll
        for (int r = 0; r < 4; ++r) {
            float mm = m[mi][r], ss = s[mi][r];
#pragma unroll
            for (int off = 1; off < 16; off <<= 1) {
                float om = __shfl_xor(mm, off, 64);
                float os = __shfl_xor(ss, off, 64);
                float nm = fmaxf(mm, om);
                ss = ss * __expf(mm - nm) + os * __expf(om - nm);
                mm = nm;
            }
            m[mi][r] = mm; s[mi][r] = ss;
        }
    if ((lane & 15) == 0) {
#pragma unroll
        for (int mi = 0; mi < 4; ++mi)
#pragma unroll
            for (int r = 0; r < 4; ++r) {
                int row = r0 + mi * 16 + g * 4 + r;
                if (row < NU) {
                    pm[chunk * NU + row] = m[mi][r];
                    ps[chunk * NU + row] = s[mi][r];
                }
            }
    }
}

// ---------------- combine partials: lse[r] = m + log(sum)
__global__ void k_lse_comb(const float* __restrict__ pm, const float* __restrict__ ps,
                           float* __restrict__ lse) {
    int r = blockIdx.x * blockDim.x + threadIdx.x;
    if (r >= NU) return;
    float m = -INFINITY;
    for (int c = 0; c < NCH; ++c) m = fmaxf(m, pm[c * NU + r]);
    float s = 0.f;
    for (int c = 0; c < NCH; ++c) s += ps[c * NU + r] * __expf(pm[c * NU + r] - m);
    lse[r] = m + __logf(s);
}

// ---------------- kernel B: recompute scores, M=256/block (64 rows/wave), out = s - lse[row]
// grid RBLK4*CBLK colblk-fast; one 128-col tile per block; LDS reused for output staging
__global__ __launch_bounds__(256) void k_out(const unsigned short* __restrict__ allemb,
                                             const float* __restrict__ lse, float* __restrict__ out) {
    __shared__ short8 Bs[3072];   // 49152 B; reused as float tile[4][16][132]
    int id = blockIdx.x;
    int rowblk = id / CBLK;
    int colblk = id % CBLK;
    int tid = threadIdx.x;
    int lane = tid & 63;
    int wave = tid >> 6;
    int r0 = rowblk * 256 + wave * 64;
    int c0 = colblk * 128;
    const unsigned short* A = allemb;
    const unsigned short* B = allemb + (size_t)NU * KD;
    int kofs = (lane >> 4) * 8;
    int g = lane >> 4;

    const unsigned short* Bt = B + (size_t)c0 * KD;
#pragma unroll
    for (int i = 0; i < 12; ++i) {
        int mm = i * 256 + tid;
        int r = mm / 24, c = mm - r * 24;
        int kt = c >> 2, gg = c & 3;
        Bs[bslot(r >> 4, kt, gg, r & 15)] = *(const short8*)(Bt + (size_t)r * KD + c * 8);
    }

    short8 a[4][6];
#pragma unroll
    for (int mi = 0; mi < 4; ++mi) {
        int ar = r0 + mi * 16 + (lane & 15);
        if (ar >= NU) ar = NU - 1;
#pragma unroll
        for (int kt = 0; kt < 6; ++kt)
            a[mi][kt] = *(const short8*)(A + (size_t)ar * KD + kt * 32 + kofs);
    }
    float l4[4][4];
#pragma unroll
    for (int mi = 0; mi < 4; ++mi)
#pragma unroll
        for (int r = 0; r < 4; ++r) {
            int row = r0 + mi * 16 + g * 4 + r;
            l4[mi][r] = lse[row >= NU ? NU - 1 : row];
        }
    __syncthreads();

    f32x4 acc[4][8];
#pragma unroll
    for (int mi = 0; mi < 4; ++mi)
#pragma unroll
        for (int nf = 0; nf < 8; ++nf) acc[mi][nf] = (f32x4){0.f, 0.f, 0.f, 0.f};
#pragma unroll
    for (int nf = 0; nf < 8; ++nf)
#pragma unroll
        for (int kt = 0; kt < 6; ++kt) {
            short8 b = Bs[bslot(nf, kt, g, lane & 15)];
#pragma unroll
            for (int mi = 0; mi < 4; ++mi)
                acc[mi][nf] = __builtin_amdgcn_mfma_f32_16x16x32_bf16(a[mi][kt], b, acc[mi][nf], 0, 0, 0);
        }
    __syncthreads();   // all B reads done -> reuse LDS as output tile

    float* tilef = (float*)Bs;                 // [4][16][132]
    float* tW = tilef + wave * 16 * 132;
#pragma unroll
    for (int mi = 0; mi < 4; ++mi) {
        int rowbase = r0 + mi * 16;
#pragma unroll
        for (int nf = 0; nf < 8; ++nf)
#pragma unroll
            for (int r = 0; r < 4; ++r)
                tW[(g * 4 + r) * 132 + nf * 16 + (lane & 15)] = acc[mi][nf][r] - l4[mi][r];
#pragma unroll
        for (int it = 0; it < 8; ++it) {
            int idx = it * 64 + lane;
            int rr = idx >> 5;
            int cc = (idx & 31) * 4;
            int row = rowbase + rr;
            if (row < NU) {
                f32x4 v = *(const f32x4*)&tW[rr * 132 + cc];
                __builtin_nontemporal_store(v, (f32x4*)&out[(size_t)row * NI + c0 + cc]);
            }
        }
    }
}

extern "C" void kernel_launch(void* const* d_in, const int* in_sizes, int n_in,
                              void* d_out, int out_size, void* d_ws, size_t ws_size,
                              hipStream_t stream) {
    const int*   uidx = (const int*)d_in[0];
    const int*   iidx = (const int*)d_in[1];
    const int*   arow = (const int*)d_in[2];
    const int*   acol = (const int*)d_in[3];
    const float* aval = (const float*)d_in[4];
    const float* ue   = (const float*)d_in[5];
    const float* ie   = (const float*)d_in[6];
    const float* gcW  = (const float*)d_in[7];
    const float* gcb  = (const float*)d_in[8];
    const float* biW  = (const float*)d_in[9];
    const float* bib  = (const float*)d_in[10];
    float* out = (float*)d_out;

    char* w = (char*)d_ws;
    unsigned short* allemb = (unsigned short*)w;  w += (size_t)NN * KD * sizeof(unsigned short);
    float* side = (float*)w;                      w += (size_t)NN * DD * sizeof(float);
    float* pm  = (float*)w;                       w += (size_t)NCH * NU * sizeof(float);
    float* ps  = (float*)w;                       w += (size_t)NCH * NU * sizeof(float);
    float* lse = (float*)w;                       w += (size_t)NU * sizeof(float);
    unsigned short* wbf = (unsigned short*)w;     w += (size_t)2 * NL * DD * DD * sizeof(unsigned short);
    int* cnt   = (int*)w;                         w += (size_t)NN * sizeof(int);
    int* rp    = (int*)w;                         w += (size_t)(NN + 4) * sizeof(int);
    int* wp    = (int*)w;                         w += (size_t)NN * sizeof(int);
    int* btot  = (int*)w;                         w += 32 * sizeof(int);
    int* boff  = (int*)w;                         w += 32 * sizeof(int);
    int2* edat = (int2*)w;                        w += (size_t)NNZS * sizeof(int2);

    unsigned short* wg_bf = wbf;                  // [NL][64][64]
    unsigned short* wb_bf = wbf + NL * DD * DD;

    k_concat<<<(NN * DD + 255) / 256, 256, 0, stream>>>(uidx, iidx, ue, ie, gcW, biW,
                                                        allemb, wbf, cnt);

    // CSR build (parallel scan)
    k_hist<<<(NNZS + 255) / 256, 256, 0, stream>>>(arow, cnt);
    k_scan1<<<SCH, 1024, 0, stream>>>(cnt, rp, btot);
    k_scan2<<<1, 64, 0, stream>>>(btot, boff);
    k_scan3<<<SCH, 1024, 0, stream>>>(cnt, boff, rp, wp);
    k_scatter<<<(NNZS + 255) / 256, 256, 0, stream>>>(arow, acol, aval, wp, edat);

    for (int l = 0; l < NL; ++l) {
        k_spmm_csr<<<3000, 256, 0, stream>>>(rp, edat, allemb + l * DD, side);
        k_dense<<<NN / 64, 256, 0, stream>>>(side, allemb, l,
                                             wg_bf + l * DD * DD, wb_bf + l * DD * DD,
                                             gcb + l * DD, bib + l * DD);
    }

    k_lse_part<<<RBLK4 * NCH, 256, 0, stream>>>(allemb, pm, ps);
    k_lse_comb<<<(NU + 255) / 256, 256, 0, stream>>>(pm, ps, lse);
    k_out<<<RBLK4 * CBLK, 256, 0, stream>>>(allemb, lse, out);
}

// Round 13
// 455.873 us; speedup vs baseline: 1.1573x; 1.1573x over previous
//
#include <hip/hip_runtime.h>
#include <hip/hip_bf16.h>
#include <math.h>

#define NU   8000
#define NI   16000
#define NN   24000
#define DD   64
#define NL   2
#define NNZS 768000
#define KD   192        // 3 * 64 concat width
#define NCH  25         // column chunks
#define ACHUNK 640      // 16000 / NCH
#define CTILES 5        // ACHUNK / 128
#define RBLK3 42        // ceil(8000/192) row blocks (M=192 per block, 48 rows/wave)
#define CBLK 125        // 16000/128 col blocks
#define SCH  24         // scan blocks

typedef __attribute__((ext_vector_type(8))) short  short8;
typedef __attribute__((ext_vector_type(4))) float  f32x4;

__device__ __forceinline__ unsigned short f2bf(float x) {
    union { float f; unsigned int u; } v; v.f = x;
    unsigned int r = v.u + 0x7fff + ((v.u >> 16) & 1);   // round-nearest-even
    return (unsigned short)(r >> 16);
}
__device__ __forceinline__ float bf2f(unsigned short u) {
    union { unsigned int u; float f; } v; v.u = ((unsigned int)u) << 16;
    return v.f;
}

// B-tile LDS layout: slot for (nf,kt,g,r16) = ((kt*8+nf)*4+g)*16+r16, XOR (g+4kt)&7
__device__ __forceinline__ int bslot(int nf, int kt, int g, int r16) {
    return ((((kt * 8 + nf) * 4 + g) * 16) + r16) ^ ((g + 4 * kt) & 7);
}

// ---------------- concat -> all_emb[:,0:64] bf16; zero hist; W -> bf16
__global__ void k_concat(const int* __restrict__ uidx, const int* __restrict__ iidx,
                         const float* __restrict__ ue, const float* __restrict__ ie,
                         const float* __restrict__ gcW, const float* __restrict__ biW,
                         unsigned short* __restrict__ allemb,
                         unsigned short* __restrict__ wbf, int* __restrict__ cnt) {
    int t = blockIdx.x * blockDim.x + threadIdx.x;
    if (t < NN) cnt[t] = 0;
    if (t < NL * DD * DD) {
        wbf[t] = f2bf(gcW[t]);
        wbf[NL * DD * DD + t] = f2bf(biW[t]);
    }
    if (t >= NN * DD) return;
    int n = t >> 6, d = t & 63;
    float v = (n < NU) ? ue[uidx[n] * DD + d] : ie[iidx[n - NU] * DD + d];
    allemb[(size_t)n * KD + d] = f2bf(v);
}

// ---------------- CSR build: histogram -> parallel 3-phase scan -> scatter
__global__ void k_hist(const int* __restrict__ rows, int* __restrict__ cnt) {
    int e = blockIdx.x * blockDim.x + threadIdx.x;
    if (e < NNZS) atomicAdd(&cnt[rows[e]], 1);
}

__global__ __launch_bounds__(1024) void k_scan1(const int* __restrict__ cnt,
                                                int* __restrict__ rp, int* __restrict__ btot) {
    __shared__ int wsum[16];
    int tid = threadIdx.x, lane = tid & 63, wid = tid >> 6;
    int i = blockIdx.x * 1024 + tid;
    int v = (i < NN) ? cnt[i] : 0;
    int x = v;
#pragma unroll
    for (int off = 1; off < 64; off <<= 1) {
        int t = __shfl_up(x, off, 64);
        if (lane >= off) x += t;
    }
    if (lane == 63) wsum[wid] = x;
    __syncthreads();
    if (tid < 16) {
        int y = wsum[tid];
#pragma unroll
        for (int off = 1; off < 16; off <<= 1) {
            int t = __shfl_up(y, off, 64);
            if (tid >= off) y += t;
        }
        wsum[tid] = y;
    }
    __syncthreads();
    int incl = x + (wid ? wsum[wid - 1] : 0);
    if (i < NN) rp[i + 1] = incl;
    if (tid == 0) btot[blockIdx.x] = wsum[15];
}

__global__ void k_scan2(const int* __restrict__ btot, int* __restrict__ boff) {
    int tid = threadIdx.x;   // 64 threads
    int v = (tid < SCH) ? btot[tid] : 0;
    int x = v;
#pragma unroll
    for (int off = 1; off < 32; off <<= 1) {
        int t = __shfl_up(x, off, 64);
        if (tid >= off) x += t;
    }
    if (tid < SCH) boff[tid] = x - v;
}

__global__ __launch_bounds__(1024) void k_scan3(const int* __restrict__ cnt,
                                                const int* __restrict__ boff,
                                                int* __restrict__ rp, int* __restrict__ wp) {
    int i = blockIdx.x * 1024 + threadIdx.x;
    if (i == 0) rp[0] = 0;
    if (i >= NN) return;
    int g = rp[i + 1] + boff[blockIdx.x];
    rp[i + 1] = g;
    wp[i] = g - cnt[i];
}

__global__ void k_scatter(const int* __restrict__ rows, const int* __restrict__ cols,
                          const float* __restrict__ vals, int* __restrict__ wp,
                          int2* __restrict__ edat) {
    int e = blockIdx.x * blockDim.x + threadIdx.x;
    if (e >= NNZS) return;
    int r = rows[e];
    int pos = atomicAdd(&wp[r], 1);
    edat[pos] = make_int2(cols[e], __float_as_int(vals[e]));
}

// ---------------- side[r] = sum_e val_e * feat[col_e]: bf16 gather, one wave/row, full TLP
__global__ void k_spmm_csr(const int* __restrict__ rp, const int2* __restrict__ edat,
                           const unsigned short* __restrict__ feat, float* __restrict__ side) {
    int lane = threadIdx.x & 63;
    int wave = (blockIdx.x * blockDim.x + threadIdx.x) >> 6;
    int nw   = (gridDim.x * blockDim.x) >> 6;
    for (int r = wave; r < NN; r += nw) {
        int e0 = rp[r], e1 = rp[r + 1];
        float acc = 0.f;
        int e = e0;
        for (; e + 8 <= e1; e += 8) {
            int2 d[8];
#pragma unroll
            for (int j = 0; j < 8; ++j) d[j] = edat[e + j];
#pragma unroll
            for (int j = 0; j < 8; ++j)
                acc = fmaf(__int_as_float(d[j].y), bf2f(feat[(size_t)d[j].x * KD + lane]), acc);
        }
        for (; e < e1; ++e) {
            int2 d = edat[e];
            acc = fmaf(__int_as_float(d.y), bf2f(feat[(size_t)d.x * KD + lane]), acc);
        }
        side[(size_t)r * DD + lane] = acc;
    }
}

// ---------------- dense layer via MFMA
__global__ __launch_bounds__(256) void k_dense(const float* __restrict__ side,
                        unsigned short* __restrict__ allemb, int l,
                        const unsigned short* __restrict__ wg_bf,
                        const unsigned short* __restrict__ wb_bf,
                        const float* __restrict__ gcb, const float* __restrict__ bib) {
    int lane = threadIdx.x & 63;
    int wave = threadIdx.x >> 6;
    int n0 = (blockIdx.x * 4 + wave) * 16;
    int nrow = lane & 15;
    int kofs = (lane >> 4) * 8;
    const unsigned short* feat = allemb + l * DD;

    short8 bg[4][2], bb[4][2];
#pragma unroll
    for (int nf = 0; nf < 4; ++nf)
#pragma unroll
        for (int kt = 0; kt < 2; ++kt) {
            bg[nf][kt] = *(const short8*)(wg_bf + (nf * 16 + nrow) * DD + kt * 32 + kofs);
            bb[nf][kt] = *(const short8*)(wb_bf + (nf * 16 + nrow) * DD + kt * 32 + kofs);
        }

    short8 a1[2], a2[2];
    const float* sp = side + (size_t)(n0 + nrow) * DD;
    const unsigned short* ep = feat + (size_t)(n0 + nrow) * KD;
#pragma unroll
    for (int kt = 0; kt < 2; ++kt) {
        int o = kt * 32 + kofs;
#pragma unroll
        for (int j = 0; j < 8; ++j) {
            float s = sp[o + j];
            float e = bf2f(ep[o + j]);
            a1[kt][j] = (short)f2bf(s);
            a2[kt][j] = (short)f2bf(e * s);
        }
    }

    f32x4 acc1[4], acc2[4];
#pragma unroll
    for (int nf = 0; nf < 4; ++nf) { acc1[nf] = (f32x4){0,0,0,0}; acc2[nf] = (f32x4){0,0,0,0}; }
#pragma unroll
    for (int nf = 0; nf < 4; ++nf)
#pragma unroll
        for (int kt = 0; kt < 2; ++kt) {
            acc1[nf] = __builtin_amdgcn_mfma_f32_16x16x32_bf16(a1[kt], bg[nf][kt], acc1[nf], 0, 0, 0);
            acc2[nf] = __builtin_amdgcn_mfma_f32_16x16x32_bf16(a2[kt], bb[nf][kt], acc2[nf], 0, 0, 0);
        }

    int g = lane >> 4;
#pragma unroll
    for (int nf = 0; nf < 4; ++nf) {
        int o = nf * 16 + nrow;
        float b1 = gcb[o], b2 = bib[o];
#pragma unroll
        for (int r = 0; r < 4; ++r) {
            int node = n0 + g * 4 + r;
            float v1 = acc1[nf][r] + b1;
            float v2 = acc2[nf][r] + b2;
            v1 = v1 > 0.f ? v1 : 0.01f * v1;
            v2 = v2 > 0.f ? v2 : 0.01f * v2;
            allemb[(size_t)node * KD + (l + 1) * DD + o] = f2bf(v1 + v2);
        }
    }
}

// ---------------- kernel A: online (m, sum-exp) partials, M=192/block (48 rows/wave, mi=3)
__global__ __launch_bounds__(256) void k_lse_part(const unsigned short* __restrict__ allemb,
                                                  float* __restrict__ pm, float* __restrict__ ps) {
    __shared__ short8 Bs[3072];   // 49152 B
    int id = blockIdx.x;
    int rowblk = id % RBLK3;
    int chunk  = id / RBLK3;
    int tid = threadIdx.x;
    int lane = tid & 63;
    int wave = tid >> 6;
    int r0 = rowblk * 192 + wave * 48;
    int c0 = chunk * ACHUNK;
    const unsigned short* A = allemb;
    const unsigned short* B = allemb + (size_t)NU * KD;
    int kofs = (lane >> 4) * 8;
    int g = lane >> 4;

    short8 a[3][6];
#pragma unroll
    for (int mi = 0; mi < 3; ++mi) {
        int ar = r0 + mi * 16 + (lane & 15);
        if (ar >= NU) ar = NU - 1;    // ragged row guard
#pragma unroll
        for (int kt = 0; kt < 6; ++kt)
            a[mi][kt] = *(const short8*)(A + (size_t)ar * KD + kt * 32 + kofs);
    }

    float m[3][4], s[3][4];
#pragma unroll
    for (int mi = 0; mi < 3; ++mi)
#pragma unroll
        for (int r = 0; r < 4; ++r) { m[mi][r] = -INFINITY; s[mi][r] = 0.f; }

    for (int t = 0; t < CTILES; ++t) {
        const unsigned short* Bt = B + (size_t)(c0 + t * 128) * KD;
        __syncthreads();
#pragma unroll
        for (int i = 0; i < 12; ++i) {
            int mm = i * 256 + tid;
            int r = mm / 24, c = mm - r * 24;
            int kt = c >> 2, gg = c & 3;
            Bs[bslot(r >> 4, kt, gg, r & 15)] = *(const short8*)(Bt + (size_t)r * KD + c * 8);
        }
        __syncthreads();

        f32x4 acc[3][8];
#pragma unroll
        for (int mi = 0; mi < 3; ++mi)
#pragma unroll
            for (int nf = 0; nf < 8; ++nf) acc[mi][nf] = (f32x4){0.f, 0.f, 0.f, 0.f};
#pragma unroll
        for (int nf = 0; nf < 8; ++nf)
#pragma unroll
            for (int kt = 0; kt < 6; ++kt) {
                short8 b = Bs[bslot(nf, kt, g, lane & 15)];
#pragma unroll
                for (int mi = 0; mi < 3; ++mi)
                    acc[mi][nf] = __builtin_amdgcn_mfma_f32_16x16x32_bf16(a[mi][kt], b, acc[mi][nf], 0, 0, 0);
            }
#pragma unroll
        for (int mi = 0; mi < 3; ++mi)
#pragma unroll
            for (int r = 0; r < 4; ++r) {
                float lm = acc[mi][0][r];
#pragma unroll
                for (int nf = 1; nf < 8; ++nf) lm = fmaxf(lm, acc[mi][nf][r]);
                float nm = fmaxf(m[mi][r], lm);
                float p = 0.f;
#pragma unroll
                for (int nf = 0; nf < 8; ++nf) p += __expf(acc[mi][nf][r] - nm);
                s[mi][r] = s[mi][r] * __expf(m[mi][r] - nm) + p;
                m[mi][r] = nm;
            }
    }
#pragma unroll
    for (int mi = 0; mi < 3; ++mi)
#pragma unroll
        for (int r = 0; r < 4; ++r) {
            float mm = m[mi][r], ss = s[mi][r];
#pragma unroll
            for (int off = 1; off < 16; off <<= 1) {
                float om = __shfl_xor(mm, off, 64);
                float os = __shfl_xor(ss, off, 64);
                float nm = fmaxf(mm, om);
                ss = ss * __expf(mm - nm) + os * __expf(om - nm);
                mm = nm;
            }
            m[mi][r] = mm; s[mi][r] = ss;
        }
    if ((lane & 15) == 0) {
#pragma unroll
        for (int mi = 0; mi < 3; ++mi)
#pragma unroll
            for (int r = 0; r < 4; ++r) {
                int row = r0 + mi * 16 + g * 4 + r;
                if (row < NU) {
                    pm[chunk * NU + row] = m[mi][r];
                    ps[chunk * NU + row] = s[mi][r];
                }
            }
    }
}

// ---------------- combine partials: lse[r] = m + log(sum)
__global__ void k_lse_comb(const float* __restrict__ pm, const float* __restrict__ ps,
                           float* __restrict__ lse) {
    int r = blockIdx.x * blockDim.x + threadIdx.x;
    if (r >= NU) return;
    float m = -INFINITY;
    for (int c = 0; c < NCH; ++c) m = fmaxf(m, pm[c * NU + r]);
    float s = 0.f;
    for (int c = 0; c < NCH; ++c) s += ps[c * NU + r] * __expf(pm[c * NU + r] - m);
    lse[r] = m + __logf(s);
}

// ---------------- kernel B: recompute scores, M=192/block (48 rows/wave), out = s - lse[row]
// grid RBLK3*CBLK colblk-fast; one 128-col tile per block; LDS reused for output staging
__global__ __launch_bounds__(256) void k_out(const unsigned short* __restrict__ allemb,
                                             const float* __restrict__ lse, float* __restrict__ out) {
    __shared__ short8 Bs[3072];   // 49152 B; reused as float tile[4][16][132]
    int id = blockIdx.x;
    int rowblk = id / CBLK;
    int colblk = id % CBLK;
    int tid = threadIdx.x;
    int lane = tid & 63;
    int wave = tid >> 6;
    int r0 = rowblk * 192 + wave * 48;
    int c0 = colblk * 128;
    const unsigned short* A = allemb;
    const unsigned short* B = allemb + (size_t)NU * KD;
    int kofs = (lane >> 4) * 8;
    int g = lane >> 4;

    const unsigned short* Bt = B + (size_t)c0 * KD;
#pragma unroll
    for (int i = 0; i < 12; ++i) {
        int mm = i * 256 + tid;
        int r = mm / 24, c = mm - r * 24;
        int kt = c >> 2, gg = c & 3;
        Bs[bslot(r >> 4, kt, gg, r & 15)] = *(const short8*)(Bt + (size_t)r * KD + c * 8);
    }

    short8 a[3][6];
#pragma unroll
    for (int mi = 0; mi < 3; ++mi) {
        int ar = r0 + mi * 16 + (lane & 15);
        if (ar >= NU) ar = NU - 1;
#pragma unroll
        for (int kt = 0; kt < 6; ++kt)
            a[mi][kt] = *(const short8*)(A + (size_t)ar * KD + kt * 32 + kofs);
    }
    float l4[3][4];
#pragma unroll
    for (int mi = 0; mi < 3; ++mi)
#pragma unroll
        for (int r = 0; r < 4; ++r) {
            int row = r0 + mi * 16 + g * 4 + r;
            l4[mi][r] = lse[row >= NU ? NU - 1 : row];
        }
    __syncthreads();

    f32x4 acc[3][8];
#pragma unroll
    for (int mi = 0; mi < 3; ++mi)
#pragma unroll
        for (int nf = 0; nf < 8; ++nf) acc[mi][nf] = (f32x4){0.f, 0.f, 0.f, 0.f};
#pragma unroll
    for (int nf = 0; nf < 8; ++nf)
#pragma unroll
        for (int kt = 0; kt < 6; ++kt) {
            short8 b = Bs[bslot(nf, kt, g, lane & 15)];
#pragma unroll
            for (int mi = 0; mi < 3; ++mi)
                acc[mi][nf] = __builtin_amdgcn_mfma_f32_16x16x32_bf16(a[mi][kt], b, acc[mi][nf], 0, 0, 0);
        }
    __syncthreads();   // all B reads done -> reuse LDS as output tile

    float* tilef = (float*)Bs;                 // [4][16][132]
    float* tW = tilef + wave * 16 * 132;
#pragma unroll
    for (int mi = 0; mi < 3; ++mi) {
        int rowbase = r0 + mi * 16;
#pragma unroll
        for (int nf = 0; nf < 8; ++nf)
#pragma unroll
            for (int r = 0; r < 4; ++r)
                tW[(g * 4 + r) * 132 + nf * 16 + (lane & 15)] = acc[mi][nf][r] - l4[mi][r];
#pragma unroll
        for (int it = 0; it < 8; ++it) {
            int idx = it * 64 + lane;
            int rr = idx >> 5;
            int cc = (idx & 31) * 4;
            int row = rowbase + rr;
            if (row < NU) {
                f32x4 v = *(const f32x4*)&tW[rr * 132 + cc];
                __builtin_nontemporal_store(v, (f32x4*)&out[(size_t)row * NI + c0 + cc]);
            }
        }
    }
}

extern "C" void kernel_launch(void* const* d_in, const int* in_sizes, int n_in,
                              void* d_out, int out_size, void* d_ws, size_t ws_size,
                              hipStream_t stream) {
    const int*   uidx = (const int*)d_in[0];
    const int*   iidx = (const int*)d_in[1];
    const int*   arow = (const int*)d_in[2];
    const int*   acol = (const int*)d_in[3];
    const float* aval = (const float*)d_in[4];
    const float* ue   = (const float*)d_in[5];
    const float* ie   = (const float*)d_in[6];
    const float* gcW  = (const float*)d_in[7];
    const float* gcb  = (const float*)d_in[8];
    const float* biW  = (const float*)d_in[9];
    const float* bib  = (const float*)d_in[10];
    float* out = (float*)d_out;

    char* w = (char*)d_ws;
    unsigned short* allemb = (unsigned short*)w;  w += (size_t)NN * KD * sizeof(unsigned short);
    float* side = (float*)w;                      w += (size_t)NN * DD * sizeof(float);
    float* pm  = (float*)w;                       w += (size_t)NCH * NU * sizeof(float);
    float* ps  = (float*)w;                       w += (size_t)NCH * NU * sizeof(float);
    float* lse = (float*)w;                       w += (size_t)NU * sizeof(float);
    unsigned short* wbf = (unsigned short*)w;     w += (size_t)2 * NL * DD * DD * sizeof(unsigned short);
    int* cnt   = (int*)w;                         w += (size_t)NN * sizeof(int);
    int* rp    = (int*)w;                         w += (size_t)(NN + 4) * sizeof(int);
    int* wp    = (int*)w;                         w += (size_t)NN * sizeof(int);
    int* btot  = (int*)w;                         w += 32 * sizeof(int);
    int* boff  = (int*)w;                         w += 32 * sizeof(int);
    int2* edat = (int2*)w;                        w += (size_t)NNZS * sizeof(int2);

    unsigned short* wg_bf = wbf;                  // [NL][64][64]
    unsigned short* wb_bf = wbf + NL * DD * DD;

    k_concat<<<(NN * DD + 255) / 256, 256, 0, stream>>>(uidx, iidx, ue, ie, gcW, biW,
                                                        allemb, wbf, cnt);

    // CSR build (parallel scan)
    k_hist<<<(NNZS + 255) / 256, 256, 0, stream>>>(arow, cnt);
    k_scan1<<<SCH, 1024, 0, stream>>>(cnt, rp, btot);
    k_scan2<<<1, 64, 0, stream>>>(btot, boff);
    k_scan3<<<SCH, 1024, 0, stream>>>(cnt, boff, rp, wp);
    k_scatter<<<(NNZS + 255) / 256, 256, 0, stream>>>(arow, acol, aval, wp, edat);

    for (int l = 0; l < NL; ++l) {
        k_spmm_csr<<<3000, 256, 0, stream>>>(rp, edat, allemb + l * DD, side);
        k_dense<<<NN / 64, 256, 0, stream>>>(side, allemb, l,
                                             wg_bf + l * DD * DD, wb_bf + l * DD * DD,
                                             gcb + l * DD, bib + l * DD);
    }

    k_lse_part<<<RBLK3 * NCH, 256, 0, stream>>>(allemb, pm, ps);
    k_lse_comb<<<(NU + 255) / 256, 256, 0, stream>>>(pm, ps, lse);
    k_out<<<RBLK3 * CBLK, 256, 0, stream>>>(allemb, lse, out);
}

// Round 14
// 452.694 us; speedup vs baseline: 1.1654x; 1.0070x over previous
//
#include <hip/hip_runtime.h>
#include <hip/hip_bf16.h>
#include <math.h>

#define NU   8000
#define NI   16000
#define NN   24000
#define DD   64
#define NL   2
#define NNZS 768000
#define KD   192        // 3 * 64 concat width
#define NCH  25         // column chunks
#define ACHUNK 640      // 16000 / NCH
#define CTILES 5        // ACHUNK / 128
#define RBLK3 42        // ceil(8000/192) row blocks (M=192 per block, 48 rows/wave)
#define CBLK 125        // 16000/128 col blocks
#define SCH  24         // scan blocks

typedef __attribute__((ext_vector_type(8))) short  short8;
typedef __attribute__((ext_vector_type(4))) float  f32x4;

__device__ __forceinline__ unsigned short f2bf(float x) {
    union { float f; unsigned int u; } v; v.f = x;
    unsigned int r = v.u + 0x7fff + ((v.u >> 16) & 1);   // round-nearest-even
    return (unsigned short)(r >> 16);
}
__device__ __forceinline__ float bf2f(unsigned short u) {
    union { unsigned int u; float f; } v; v.u = ((unsigned int)u) << 16;
    return v.f;
}

// B-tile LDS layout: slot for (nf,kt,g,r16) = ((kt*8+nf)*4+g)*16+r16, XOR (g+4kt)&7
__device__ __forceinline__ int bslot(int nf, int kt, int g, int r16) {
    return ((((kt * 8 + nf) * 4 + g) * 16) + r16) ^ ((g + 4 * kt) & 7);
}

// ---------------- concat -> all_emb[:,0:64] bf16; zero hist; W -> bf16
__global__ void k_concat(const int* __restrict__ uidx, const int* __restrict__ iidx,
                         const float* __restrict__ ue, const float* __restrict__ ie,
                         const float* __restrict__ gcW, const float* __restrict__ biW,
                         unsigned short* __restrict__ allemb,
                         unsigned short* __restrict__ wbf, int* __restrict__ cnt) {
    int t = blockIdx.x * blockDim.x + threadIdx.x;
    if (t < NN) cnt[t] = 0;
    if (t < NL * DD * DD) {
        wbf[t] = f2bf(gcW[t]);
        wbf[NL * DD * DD + t] = f2bf(biW[t]);
    }
    if (t >= NN * DD) return;
    int n = t >> 6, d = t & 63;
    float v = (n < NU) ? ue[uidx[n] * DD + d] : ie[iidx[n - NU] * DD + d];
    allemb[(size_t)n * KD + d] = f2bf(v);
}

// ---------------- CSR build: histogram -> parallel 3-phase scan -> scatter
__global__ void k_hist(const int* __restrict__ rows, int* __restrict__ cnt) {
    int e = blockIdx.x * blockDim.x + threadIdx.x;
    if (e < NNZS) atomicAdd(&cnt[rows[e]], 1);
}

__global__ __launch_bounds__(1024) void k_scan1(const int* __restrict__ cnt,
                                                int* __restrict__ rp, int* __restrict__ btot) {
    __shared__ int wsum[16];
    int tid = threadIdx.x, lane = tid & 63, wid = tid >> 6;
    int i = blockIdx.x * 1024 + tid;
    int v = (i < NN) ? cnt[i] : 0;
    int x = v;
#pragma unroll
    for (int off = 1; off < 64; off <<= 1) {
        int t = __shfl_up(x, off, 64);
        if (lane >= off) x += t;
    }
    if (lane == 63) wsum[wid] = x;
    __syncthreads();
    if (tid < 16) {
        int y = wsum[tid];
#pragma unroll
        for (int off = 1; off < 16; off <<= 1) {
            int t = __shfl_up(y, off, 64);
            if (tid >= off) y += t;
        }
        wsum[tid] = y;
    }
    __syncthreads();
    int incl = x + (wid ? wsum[wid - 1] : 0);
    if (i < NN) rp[i + 1] = incl;
    if (tid == 0) btot[blockIdx.x] = wsum[15];
}

__global__ void k_scan2(const int* __restrict__ btot, int* __restrict__ boff) {
    int tid = threadIdx.x;   // 64 threads
    int v = (tid < SCH) ? btot[tid] : 0;
    int x = v;
#pragma unroll
    for (int off = 1; off < 32; off <<= 1) {
        int t = __shfl_up(x, off, 64);
        if (tid >= off) x += t;
    }
    if (tid < SCH) boff[tid] = x - v;
}

__global__ __launch_bounds__(1024) void k_scan3(const int* __restrict__ cnt,
                                                const int* __restrict__ boff,
                                                int* __restrict__ rp, int* __restrict__ wp) {
    int i = blockIdx.x * 1024 + threadIdx.x;
    if (i == 0) rp[0] = 0;
    if (i >= NN) return;
    int g = rp[i + 1] + boff[blockIdx.x];
    rp[i + 1] = g;
    wp[i] = g - cnt[i];
}

__global__ void k_scatter(const int* __restrict__ rows, const int* __restrict__ cols,
                          const float* __restrict__ vals, int* __restrict__ wp,
                          int2* __restrict__ edat) {
    int e = blockIdx.x * blockDim.x + threadIdx.x;
    if (e >= NNZS) return;
    int r = rows[e];
    int pos = atomicAdd(&wp[r], 1);
    edat[pos] = make_int2(cols[e], __float_as_int(vals[e]));
}

// ---------------- side[r] = sum_e val_e * feat[col_e]: bf16 gather, one wave/row, full TLP
__global__ void k_spmm_csr(const int* __restrict__ rp, const int2* __restrict__ edat,
                           const unsigned short* __restrict__ feat, float* __restrict__ side) {
    int lane = threadIdx.x & 63;
    int wave = (blockIdx.x * blockDim.x + threadIdx.x) >> 6;
    int nw   = (gridDim.x * blockDim.x) >> 6;
    for (int r = wave; r < NN; r += nw) {
        int e0 = rp[r], e1 = rp[r + 1];
        float acc = 0.f;
        int e = e0;
        for (; e + 8 <= e1; e += 8) {
            int2 d[8];
#pragma unroll
            for (int j = 0; j < 8; ++j) d[j] = edat[e + j];
#pragma unroll
            for (int j = 0; j < 8; ++j)
                acc = fmaf(__int_as_float(d[j].y), bf2f(feat[(size_t)d[j].x * KD + lane]), acc);
        }
        for (; e < e1; ++e) {
            int2 d = edat[e];
            acc = fmaf(__int_as_float(d.y), bf2f(feat[(size_t)d.x * KD + lane]), acc);
        }
        side[(size_t)r * DD + lane] = acc;
    }
}

// ---------------- dense layer via MFMA
__global__ __launch_bounds__(256) void k_dense(const float* __restrict__ side,
                        unsigned short* __restrict__ allemb, int l,
                        const unsigned short* __restrict__ wg_bf,
                        const unsigned short* __restrict__ wb_bf,
                        const float* __restrict__ gcb, const float* __restrict__ bib) {
    int lane = threadIdx.x & 63;
    int wave = threadIdx.x >> 6;
    int n0 = (blockIdx.x * 4 + wave) * 16;
    int nrow = lane & 15;
    int kofs = (lane >> 4) * 8;
    const unsigned short* feat = allemb + l * DD;

    short8 bg[4][2], bb[4][2];
#pragma unroll
    for (int nf = 0; nf < 4; ++nf)
#pragma unroll
        for (int kt = 0; kt < 2; ++kt) {
            bg[nf][kt] = *(const short8*)(wg_bf + (nf * 16 + nrow) * DD + kt * 32 + kofs);
            bb[nf][kt] = *(const short8*)(wb_bf + (nf * 16 + nrow) * DD + kt * 32 + kofs);
        }

    short8 a1[2], a2[2];
    const float* sp = side + (size_t)(n0 + nrow) * DD;
    const unsigned short* ep = feat + (size_t)(n0 + nrow) * KD;
#pragma unroll
    for (int kt = 0; kt < 2; ++kt) {
        int o = kt * 32 + kofs;
#pragma unroll
        for (int j = 0; j < 8; ++j) {
            float s = sp[o + j];
            float e = bf2f(ep[o + j]);
            a1[kt][j] = (short)f2bf(s);
            a2[kt][j] = (short)f2bf(e * s);
        }
    }

    f32x4 acc1[4], acc2[4];
#pragma unroll
    for (int nf = 0; nf < 4; ++nf) { acc1[nf] = (f32x4){0,0,0,0}; acc2[nf] = (f32x4){0,0,0,0}; }
#pragma unroll
    for (int nf = 0; nf < 4; ++nf)
#pragma unroll
        for (int kt = 0; kt < 2; ++kt) {
            acc1[nf] = __builtin_amdgcn_mfma_f32_16x16x32_bf16(a1[kt], bg[nf][kt], acc1[nf], 0, 0, 0);
            acc2[nf] = __builtin_amdgcn_mfma_f32_16x16x32_bf16(a2[kt], bb[nf][kt], acc2[nf], 0, 0, 0);
        }

    int g = lane >> 4;
#pragma unroll
    for (int nf = 0; nf < 4; ++nf) {
        int o = nf * 16 + nrow;
        float b1 = gcb[o], b2 = bib[o];
#pragma unroll
        for (int r = 0; r < 4; ++r) {
            int node = n0 + g * 4 + r;
            float v1 = acc1[nf][r] + b1;
            float v2 = acc2[nf][r] + b2;
            v1 = v1 > 0.f ? v1 : 0.01f * v1;
            v2 = v2 > 0.f ? v2 : 0.01f * v2;
            allemb[(size_t)node * KD + (l + 1) * DD + o] = f2bf(v1 + v2);
        }
    }
}

// ---------------- kernel A: online (m, sum-exp) partials, M=192/block (48 rows/wave, mi=3)
__global__ __launch_bounds__(256) void k_lse_part(const unsigned short* __restrict__ allemb,
                                                  float* __restrict__ pm, float* __restrict__ ps) {
    __shared__ short8 Bs[3072];   // 49152 B
    int id = blockIdx.x;
    int rowblk = id % RBLK3;
    int chunk  = id / RBLK3;
    int tid = threadIdx.x;
    int lane = tid & 63;
    int wave = tid >> 6;
    int r0 = rowblk * 192 + wave * 48;
    int c0 = chunk * ACHUNK;
    const unsigned short* A = allemb;
    const unsigned short* B = allemb + (size_t)NU * KD;
    int kofs = (lane >> 4) * 8;
    int g = lane >> 4;

    short8 a[3][6];
#pragma unroll
    for (int mi = 0; mi < 3; ++mi) {
        int ar = r0 + mi * 16 + (lane & 15);
        if (ar >= NU) ar = NU - 1;    // ragged row guard
#pragma unroll
        for (int kt = 0; kt < 6; ++kt)
            a[mi][kt] = *(const short8*)(A + (size_t)ar * KD + kt * 32 + kofs);
    }

    float m[3][4], s[3][4];
#pragma unroll
    for (int mi = 0; mi < 3; ++mi)
#pragma unroll
        for (int r = 0; r < 4; ++r) { m[mi][r] = -INFINITY; s[mi][r] = 0.f; }

    for (int t = 0; t < CTILES; ++t) {
        const unsigned short* Bt = B + (size_t)(c0 + t * 128) * KD;
        __syncthreads();
#pragma unroll
        for (int i = 0; i < 12; ++i) {
            int mm = i * 256 + tid;
            int r = mm / 24, c = mm - r * 24;
            int kt = c >> 2, gg = c & 3;
            Bs[bslot(r >> 4, kt, gg, r & 15)] = *(const short8*)(Bt + (size_t)r * KD + c * 8);
        }
        __syncthreads();

        f32x4 acc[3][8];
#pragma unroll
        for (int mi = 0; mi < 3; ++mi)
#pragma unroll
            for (int nf = 0; nf < 8; ++nf) acc[mi][nf] = (f32x4){0.f, 0.f, 0.f, 0.f};
#pragma unroll
        for (int nf = 0; nf < 8; ++nf)
#pragma unroll
            for (int kt = 0; kt < 6; ++kt) {
                short8 b = Bs[bslot(nf, kt, g, lane & 15)];
#pragma unroll
                for (int mi = 0; mi < 3; ++mi)
                    acc[mi][nf] = __builtin_amdgcn_mfma_f32_16x16x32_bf16(a[mi][kt], b, acc[mi][nf], 0, 0, 0);
            }
#pragma unroll
        for (int mi = 0; mi < 3; ++mi)
#pragma unroll
            for (int r = 0; r < 4; ++r) {
                float lm = acc[mi][0][r];
#pragma unroll
                for (int nf = 1; nf < 8; ++nf) lm = fmaxf(lm, acc[mi][nf][r]);
                float nm = fmaxf(m[mi][r], lm);
                float p = 0.f;
#pragma unroll
                for (int nf = 0; nf < 8; ++nf) p += __expf(acc[mi][nf][r] - nm);
                s[mi][r] = s[mi][r] * __expf(m[mi][r] - nm) + p;
                m[mi][r] = nm;
            }
    }
#pragma unroll
    for (int mi = 0; mi < 3; ++mi)
#pragma unroll
        for (int r = 0; r < 4; ++r) {
            float mm = m[mi][r], ss = s[mi][r];
#pragma unroll
            for (int off = 1; off < 16; off <<= 1) {
                float om = __shfl_xor(mm, off, 64);
                float os = __shfl_xor(ss, off, 64);
                float nm = fmaxf(mm, om);
                ss = ss * __expf(mm - nm) + os * __expf(om - nm);
                mm = nm;
            }
            m[mi][r] = mm; s[mi][r] = ss;
        }
    if ((lane & 15) == 0) {
#pragma unroll
        for (int mi = 0; mi < 3; ++mi)
#pragma unroll
            for (int r = 0; r < 4; ++r) {
                int row = r0 + mi * 16 + g * 4 + r;
                if (row < NU) {
                    pm[chunk * NU + row] = m[mi][r];
                    ps[chunk * NU + row] = s[mi][r];
                }
            }
    }
}

// ---------------- combine partials: lse[r] = m + log(sum)
__global__ void k_lse_comb(const float* __restrict__ pm, const float* __restrict__ ps,
                           float* __restrict__ lse) {
    int r = blockIdx.x * blockDim.x + threadIdx.x;
    if (r >= NU) return;
    float m = -INFINITY;
    for (int c = 0; c < NCH; ++c) m = fmaxf(m, pm[c * NU + r]);
    float s = 0.f;
    for (int c = 0; c < NCH; ++c) s += ps[c * NU + r] * __expf(pm[c * NU + r] - m);
    lse[r] = m + __logf(s);
}

// ---------------- kernel B: recompute scores, M=192/block (48 rows/wave), out = s - lse[row]
// grid RBLK3*CBLK colblk-fast; one 128-col tile per block; LDS reused for output staging
__global__ __launch_bounds__(256) void k_out(const unsigned short* __restrict__ allemb,
                                             const float* __restrict__ lse, float* __restrict__ out) {
    __shared__ short8 Bs[3072];   // 49152 B; reused as float tile[4][16][132]
    int id = blockIdx.x;
    int rowblk = id / CBLK;
    int colblk = id % CBLK;
    int tid = threadIdx.x;
    int lane = tid & 63;
    int wave = tid >> 6;
    int r0 = rowblk * 192 + wave * 48;
    int c0 = colblk * 128;
    const unsigned short* A = allemb;
    const unsigned short* B = allemb + (size_t)NU * KD;
    int kofs = (lane >> 4) * 8;
    int g = lane >> 4;

    const unsigned short* Bt = B + (size_t)c0 * KD;
#pragma unroll
    for (int i = 0; i < 12; ++i) {
        int mm = i * 256 + tid;
        int r = mm / 24, c = mm - r * 24;
        int kt = c >> 2, gg = c & 3;
        Bs[bslot(r >> 4, kt, gg, r & 15)] = *(const short8*)(Bt + (size_t)r * KD + c * 8);
    }

    short8 a[3][6];
#pragma unroll
    for (int mi = 0; mi < 3; ++mi) {
        int ar = r0 + mi * 16 + (lane & 15);
        if (ar >= NU) ar = NU - 1;
#pragma unroll
        for (int kt = 0; kt < 6; ++kt)
            a[mi][kt] = *(const short8*)(A + (size_t)ar * KD + kt * 32 + kofs);
    }
    float l4[3][4];
#pragma unroll
    for (int mi = 0; mi < 3; ++mi)
#pragma unroll
        for (int r = 0; r < 4; ++r) {
            int row = r0 + mi * 16 + g * 4 + r;
            l4[mi][r] = lse[row >= NU ? NU - 1 : row];
        }
    __syncthreads();

    f32x4 acc[3][8];
#pragma unroll
    for (int mi = 0; mi < 3; ++mi)
#pragma unroll
        for (int nf = 0; nf < 8; ++nf) acc[mi][nf] = (f32x4){0.f, 0.f, 0.f, 0.f};
#pragma unroll
    for (int nf = 0; nf < 8; ++nf)
#pragma unroll
        for (int kt = 0; kt < 6; ++kt) {
            short8 b = Bs[bslot(nf, kt, g, lane & 15)];
#pragma unroll
            for (int mi = 0; mi < 3; ++mi)
                acc[mi][nf] = __builtin_amdgcn_mfma_f32_16x16x32_bf16(a[mi][kt], b, acc[mi][nf], 0, 0, 0);
        }
    __syncthreads();   // all B reads done -> reuse LDS as output tile

    float* tilef = (float*)Bs;                 // [4][16][132]
    float* tW = tilef + wave * 16 * 132;
#pragma unroll
    for (int mi = 0; mi < 3; ++mi) {
        int rowbase = r0 + mi * 16;
#pragma unroll
        for (int nf = 0; nf < 8; ++nf)
#pragma unroll
            for (int r = 0; r < 4; ++r)
                tW[(g * 4 + r) * 132 + nf * 16 + (lane & 15)] = acc[mi][nf][r] - l4[mi][r];
#pragma unroll
        for (int it = 0; it < 8; ++it) {
            int idx = it * 64 + lane;
            int rr = idx >> 5;
            int cc = (idx & 31) * 4;
            int row = rowbase + rr;
            if (row < NU) {
                f32x4 v = *(const f32x4*)&tW[rr * 132 + cc];
                __builtin_nontemporal_store(v, (f32x4*)&out[(size_t)row * NI + c0 + cc]);
            }
        }
    }
}

extern "C" void kernel_launch(void* const* d_in, const int* in_sizes, int n_in,
                              void* d_out, int out_size, void* d_ws, size_t ws_size,
                              hipStream_t stream) {
    const int*   uidx = (const int*)d_in[0];
    const int*   iidx = (const int*)d_in[1];
    const int*   arow = (const int*)d_in[2];
    const int*   acol = (const int*)d_in[3];
    const float* aval = (const float*)d_in[4];
    const float* ue   = (const float*)d_in[5];
    const float* ie   = (const float*)d_in[6];
    const float* gcW  = (const float*)d_in[7];
    const float* gcb  = (const float*)d_in[8];
    const float* biW  = (const float*)d_in[9];
    const float* bib  = (const float*)d_in[10];
    float* out = (float*)d_out;

    char* w = (char*)d_ws;
    unsigned short* allemb = (unsigned short*)w;  w += (size_t)NN * KD * sizeof(unsigned short);
    float* side = (float*)w;                      w += (size_t)NN * DD * sizeof(float);
    float* pm  = (float*)w;                       w += (size_t)NCH * NU * sizeof(float);
    float* ps  = (float*)w;                       w += (size_t)NCH * NU * sizeof(float);
    float* lse = (float*)w;                       w += (size_t)NU * sizeof(float);
    unsigned short* wbf = (unsigned short*)w;     w += (size_t)2 * NL * DD * DD * sizeof(unsigned short);
    int* cnt   = (int*)w;                         w += (size_t)NN * sizeof(int);
    int* rp    = (int*)w;                         w += (size_t)(NN + 4) * sizeof(int);
    int* wp    = (int*)w;                         w += (size_t)NN * sizeof(int);
    int* btot  = (int*)w;                         w += 32 * sizeof(int);
    int* boff  = (int*)w;                         w += 32 * sizeof(int);
    int2* edat = (int2*)w;                        w += (size_t)NNZS * sizeof(int2);

    unsigned short* wg_bf = wbf;                  // [NL][64][64]
    unsigned short* wb_bf = wbf + NL * DD * DD;

    k_concat<<<(NN * DD + 255) / 256, 256, 0, stream>>>(uidx, iidx, ue, ie, gcW, biW,
                                                        allemb, wbf, cnt);

    // CSR build (parallel scan)
    k_hist<<<(NNZS + 255) / 256, 256, 0, stream>>>(arow, cnt);
    k_scan1<<<SCH, 1024, 0, stream>>>(cnt, rp, btot);
    k_scan2<<<1, 64, 0, stream>>>(btot, boff);
    k_scan3<<<SCH, 1024, 0, stream>>>(cnt, boff, rp, wp);
    k_scatter<<<(NNZS + 255) / 256, 256, 0, stream>>>(arow, acol, aval, wp, edat);

    for (int l = 0; l < NL; ++l) {
        k_spmm_csr<<<3000, 256, 0, stream>>>(rp, edat, allemb + l * DD, side);
        k_dense<<<NN / 64, 256, 0, stream>>>(side, allemb, l,
                                             wg_bf + l * DD * DD, wb_bf + l * DD * DD,
                                             gcb + l * DD, bib + l * DD);
    }

    k_lse_part<<<RBLK3 * NCH, 256, 0, stream>>>(allemb, pm, ps);
    k_lse_comb<<<(NU + 255) / 256, 256, 0, stream>>>(pm, ps, lse);
    k_out<<<RBLK3 * CBLK, 256, 0, stream>>>(allemb, lse, out);
}